// Round 2
// baseline (523.518 us; speedup 1.0000x reference)
//
#include <hip/hip_runtime.h>

#define NUM_CODES 1024
#define DIM 64
#define ROWS_PER_BLOCK 256
#define RBATCH 8
#define MAIN_THREADS 1024
#define T_LEN 2048

// monotone order-preserving map float -> u32 (min of map == map of min)
__device__ __forceinline__ unsigned int fmap32(float s) {
    unsigned int b = __float_as_uint(s);
    return (b & 0x80000000u) ? ~b : (b | 0x80000000u);
}
__device__ __forceinline__ float funmap32(unsigned int m) {
    unsigned int b = (m & 0x80000000u) ? (m & 0x7fffffffu) : ~m;
    return __uint_as_float(b);
}

__global__ void vq_init_ws(double* ws) { ws[0] = 0.0; }

__global__ void vq_finalize(const double* __restrict__ ws, float* __restrict__ out_loss, int n_el) {
    out_loss[0] = (float)(1.25 * ws[0] / (double)n_el);
}

// numpy pairwise-sum (n=64, scalar blocked path) combine tree over 8 partials
__device__ __forceinline__ float np_combine8(const float* r) {
    return __fadd_rn(__fadd_rn(__fadd_rn(r[0], r[1]), __fadd_rn(r[2], r[3])),
                     __fadd_rn(__fadd_rn(r[4], r[5]), __fadd_rn(r[6], r[7])));
}

// Block: 1024 threads. Thread t holds codebook row t in registers.
// Block handles 256 consecutive rows. Replicates numpy fp32 semantics:
//   D[n,k] = fl32( fl32(A_n + B_k) - 2*M[n,k] )
//   A_n = np-pairwise sum of x*x, B_k = np-pairwise sum of e*e,
//   M   = sequential fp32 fma chain over i (OpenBLAS sgemm k-order).
// argmin with first-index tie-break.
__global__ __launch_bounds__(MAIN_THREADS) void vq_main(
        const float* __restrict__ x,
        const float* __restrict__ cb,
        float* __restrict__ out_q,
        float* __restrict__ out_idx,
        double* __restrict__ ws_loss)
{
    const int tid  = threadIdx.x;
    const int k    = tid;        // this thread's code index
    const int lane = tid & 63;
    const int wv   = tid >> 6;   // wave id within block (0..15)

    // ---- load my codebook row into registers ----
    float e[DIM];
    const float4* cb4 = (const float4*)(cb + (size_t)k * DIM);
    #pragma unroll
    for (int i = 0; i < DIM / 4; ++i) {
        float4 v = cb4[i];
        e[4 * i + 0] = v.x; e[4 * i + 1] = v.y; e[4 * i + 2] = v.z; e[4 * i + 3] = v.w;
    }
    // ---- B_k = numpy-pairwise fp32 sum of e*e ----
    float rb8[8];
    #pragma unroll
    for (int j = 0; j < 8; ++j) rb8[j] = __fmul_rn(e[j], e[j]);
    #pragma unroll
    for (int m = 1; m < 8; ++m) {
        #pragma unroll
        for (int j = 0; j < 8; ++j)
            rb8[j] = __fadd_rn(rb8[j], __fmul_rn(e[8 * m + j], e[8 * m + j]));
    }
    const float b2 = np_combine8(rb8);

    __shared__ unsigned long long key64[RBATCH];          // (fmap32(D)<<12)|k
    __shared__ float              anorm[RBATCH];          // np-fp32 ||x||^2 per row
    __shared__ int                kstar[ROWS_PER_BLOCK];

    const int r0 = blockIdx.x * ROWS_PER_BLOCK;
    double loss_acc = 0.0;  // meaningful on tid 0 only

    for (int batch = 0; batch < ROWS_PER_BLOCK / RBATCH; ++batch) {
        const int rb = r0 + batch * RBATCH;

        if (tid < RBATCH) key64[tid] = ~0ULL;

        // ---- row norms: wave w computes A for row rb+w in numpy order ----
        if (wv < RBATCH) {
            float v  = x[(size_t)(rb + wv) * DIM + lane];
            float pp = __fmul_rn(v, v);
            // r_j = ((((p_j + p_{j+8}) + p_{j+16}) + ...) + p_{j+56}), valid on lanes 0..7
            float r = __fadd_rn(pp, __shfl_down(pp, 8, 64));
            r = __fadd_rn(r, __shfl_down(pp, 16, 64));
            r = __fadd_rn(r, __shfl_down(pp, 24, 64));
            r = __fadd_rn(r, __shfl_down(pp, 32, 64));
            r = __fadd_rn(r, __shfl_down(pp, 40, 64));
            r = __fadd_rn(r, __shfl_down(pp, 48, 64));
            r = __fadd_rn(r, __shfl_down(pp, 56, 64));
            float rr[8];
            #pragma unroll
            for (int j = 0; j < 8; ++j) rr[j] = __shfl(r, j, 64);
            float an = np_combine8(rr);
            if (lane == 0) anorm[wv] = an;
        }
        __syncthreads();

        // ---- fp32 scan: sequential fma chain per (row, k); x wave-uniform loads ----
        float acc[RBATCH];
        #pragma unroll
        for (int rr = 0; rr < RBATCH; ++rr) acc[rr] = 0.0f;
        const float* xb = x + (size_t)rb * DIM;
        #pragma unroll
        for (int i = 0; i < DIM; ++i) {
            const float ei = e[i];
            #pragma unroll
            for (int rr = 0; rr < RBATCH; ++rr)
                acc[rr] = __fmaf_rn(xb[rr * DIM + i], ei, acc[rr]);
        }
        #pragma unroll
        for (int rr = 0; rr < RBATCH; ++rr) {
            const float t1 = __fadd_rn(anorm[rr], b2);
            const float d  = __fsub_rn(t1, __fmul_rn(2.0f, acc[rr]));
            unsigned long long key =
                ((unsigned long long)fmap32(d) << 12) | (unsigned long long)k;
            #pragma unroll
            for (int off = 32; off > 0; off >>= 1) {
                unsigned long long o = __shfl_xor(key, off, 64);
                key = (o < key) ? o : key;
            }
            if (lane == 0) atomicMin(&key64[rr], key);
        }
        __syncthreads();

        if (tid == 0) {
            #pragma unroll
            for (int rr = 0; rr < RBATCH; ++rr) {
                unsigned long long w = key64[rr];
                kstar[batch * RBATCH + rr] = (int)(w & 0xFFFULL);
                loss_acc += (double)funmap32((unsigned int)(w >> 12));  // D_min = ||x-q||^2
            }
        }
        // next-iteration key64 init is by lanes 0..7 of the same wave as tid 0,
        // so program order guarantees the decode above happens first.
    }
    __syncthreads();

    // ---- epilogue: indices (as float), transposed quantized, loss partial ----
    if (tid < ROWS_PER_BLOCK) out_idx[r0 + tid] = (float)kstar[tid];

    const int bb = r0 / T_LEN;
    const int t0 = r0 % T_LEN;
    #pragma unroll
    for (int it = 0; it < (ROWS_PER_BLOCK * DIM) / MAIN_THREADS; ++it) {  // 16
        const int idx = it * MAIN_THREADS + tid;
        const int d = idx >> 8;       // 0..63
        const int t = idx & 255;      // 0..255
        out_q[((size_t)bb * DIM + d) * T_LEN + (t0 + t)] = cb[(size_t)kstar[t] * DIM + d];
    }
    if (tid == 0) atomicAdd(ws_loss, loss_acc);
}

extern "C" void kernel_launch(void* const* d_in, const int* in_sizes, int n_in,
                              void* d_out, int out_size, void* d_ws, size_t ws_size,
                              hipStream_t stream) {
    const float* x  = (const float*)d_in[0];
    const float* cb = (const float*)d_in[1];
    float* out = (float*)d_out;

    const int n_x = in_sizes[0];           // 32*2048*64 = 4194304
    const int n_rows = n_x / DIM;          // 65536

    float* out_q    = out;                    // [B, D, T] fp32
    float* out_loss = out + (size_t)n_x;      // scalar
    float* out_idx  = out + (size_t)n_x + 1;  // [B, T] indices as fp32
    double* wsd = (double*)d_ws;

    vq_init_ws<<<1, 1, 0, stream>>>(wsd);
    vq_main<<<n_rows / ROWS_PER_BLOCK, MAIN_THREADS, 0, stream>>>(x, cb, out_q, out_idx, wsd);
    vq_finalize<<<1, 1, 0, stream>>>(wsd, out_loss, n_x);
}

// Round 3
// 212.217 us; speedup vs baseline: 2.4669x; 2.4669x over previous
//
#include <hip/hip_runtime.h>

#define DIM 64
#define MTILE 128        // rows per block
#define NCHUNK 128       // codes per k-chunk
#define NCHUNKS 8        // 1024 / 128
#define THREADS 256
#define T_LEN 2048
#define PITCH 68         // 64 + 4 pad: keeps 16B alignment, spreads banks

// monotone order-preserving map float -> u32
__device__ __forceinline__ unsigned int fmap32(float s) {
    unsigned int b = __float_as_uint(s);
    return (b & 0x80000000u) ? ~b : (b | 0x80000000u);
}
__device__ __forceinline__ float funmap32(unsigned int m) {
    unsigned int b = (m & 0x80000000u) ? (m & 0x7fffffffu) : ~m;
    return __uint_as_float(b);
}

// numpy pairwise-sum (n=64 scalar blocked path) combine tree over 8 partials
__device__ __forceinline__ float np_combine8(const float* r) {
    return __fadd_rn(__fadd_rn(__fadd_rn(r[0], r[1]), __fadd_rn(r[2], r[3])),
                     __fadd_rn(__fadd_rn(r[4], r[5]), __fadd_rn(r[6], r[7])));
}

__global__ void vq_init_ws(double* ws) { ws[0] = 0.0; }

__global__ void vq_finalize(const double* __restrict__ ws, float* __restrict__ out_loss, int n_el) {
    out_loss[0] = (float)(1.25 * ws[0] / (double)n_el);
}

// Replicates numpy fp32 semantics bitwise:
//   D[n,k] = fl32( fl32(A_n + B_k) - 2*M[n,k] ),  M = sequential fp32 fma chain over i,
//   A_n, B_k = numpy pairwise (8-partial) fp32 sums.  argmin w/ first-index tie-break.
__global__ __launch_bounds__(THREADS, 2) void vq_main(
        const float* __restrict__ x,
        const float* __restrict__ cb,
        float* __restrict__ out_q,
        float* __restrict__ out_idx,
        double* __restrict__ ws_loss)
{
    __shared__ alignas(16) float xs[MTILE * PITCH];
    __shared__ alignas(16) float cs[NCHUNK * PITCH];
    __shared__ float  bnorm[1024];
    __shared__ float  anorm[MTILE];
    __shared__ int    kstar[MTILE];
    __shared__ double lossred[16];

    const int tid  = threadIdx.x;
    const int tc   = tid & 15;   // code-group id (16)
    const int tr   = tid >> 4;   // row-group id  (16)
    const int lane = tid & 63;
    const int wv   = tid >> 6;   // wave in block (0..3)
    const int r0   = blockIdx.x * MTILE;

    // ---- stage x tile, row-major padded; global reads perfectly coalesced ----
    const float4* x4 = (const float4*)x;
    #pragma unroll
    for (int it = 0; it < (MTILE * DIM / 4) / THREADS; ++it) {   // 8
        int idx = it * THREADS + tid;
        int row = idx >> 4, f4 = idx & 15;
        float4 v = x4[(size_t)(r0 + row) * 16 + f4];
        *(float4*)&xs[row * PITCH + f4 * 4] = v;
    }

    // ---- B_k for all 1024 codes (numpy register routine, bit-exact) ----
    #pragma unroll
    for (int j = 0; j < 4; ++j) {
        int k = tid * 4 + j;
        const float4* c4 = (const float4*)(cb + (size_t)k * DIM);
        float r8[8];
        {
            float4 a = c4[0], b = c4[1];
            r8[0] = __fmul_rn(a.x, a.x); r8[1] = __fmul_rn(a.y, a.y);
            r8[2] = __fmul_rn(a.z, a.z); r8[3] = __fmul_rn(a.w, a.w);
            r8[4] = __fmul_rn(b.x, b.x); r8[5] = __fmul_rn(b.y, b.y);
            r8[6] = __fmul_rn(b.z, b.z); r8[7] = __fmul_rn(b.w, b.w);
        }
        #pragma unroll
        for (int m = 1; m < 8; ++m) {
            float4 a = c4[2 * m], b = c4[2 * m + 1];
            r8[0] = __fadd_rn(r8[0], __fmul_rn(a.x, a.x));
            r8[1] = __fadd_rn(r8[1], __fmul_rn(a.y, a.y));
            r8[2] = __fadd_rn(r8[2], __fmul_rn(a.z, a.z));
            r8[3] = __fadd_rn(r8[3], __fmul_rn(a.w, a.w));
            r8[4] = __fadd_rn(r8[4], __fmul_rn(b.x, b.x));
            r8[5] = __fadd_rn(r8[5], __fmul_rn(b.y, b.y));
            r8[6] = __fadd_rn(r8[6], __fmul_rn(b.z, b.z));
            r8[7] = __fadd_rn(r8[7], __fmul_rn(b.w, b.w));
        }
        bnorm[k] = np_combine8(r8);
    }

    __syncthreads();  // xs ready for cross-thread anorm reads

    // ---- A_n for 128 rows (numpy shuffle routine, bit-identical to r1) ----
    for (int j = 0; j < MTILE / 4; ++j) {   // 32 rows per wave
        int row = wv * (MTILE / 4) + j;
        float v  = xs[row * PITCH + lane];
        float pp = __fmul_rn(v, v);
        float r = __fadd_rn(pp, __shfl_down(pp, 8, 64));
        r = __fadd_rn(r, __shfl_down(pp, 16, 64));
        r = __fadd_rn(r, __shfl_down(pp, 24, 64));
        r = __fadd_rn(r, __shfl_down(pp, 32, 64));
        r = __fadd_rn(r, __shfl_down(pp, 40, 64));
        r = __fadd_rn(r, __shfl_down(pp, 48, 64));
        r = __fadd_rn(r, __shfl_down(pp, 56, 64));
        float rr[8];
        #pragma unroll
        for (int q = 0; q < 8; ++q) rr[q] = __shfl(r, q, 64);
        if (lane == 0) anorm[row] = np_combine8(rr);
    }

    unsigned long long rowmin[8];
    #pragma unroll
    for (int r = 0; r < 8; ++r) rowmin[r] = ~0ULL;

    // ---- main k-chunk loop ----
    for (int ch = 0; ch < NCHUNKS; ++ch) {
        __syncthreads();  // previous chunk's readers done (also fences anorm/bnorm on ch=0)
        const int kc = ch * NCHUNK;
        #pragma unroll
        for (int it = 0; it < (NCHUNK * DIM / 4) / THREADS; ++it) {  // 8
            int idx = it * THREADS + tid;
            int row = idx >> 4, f4 = idx & 15;
            float4 v = ((const float4*)cb)[(size_t)(kc + row) * 16 + f4];
            *(float4*)&cs[row * PITCH + f4 * 4] = v;
        }
        __syncthreads();

        float acc[8][8];
        #pragma unroll
        for (int r = 0; r < 8; ++r)
            #pragma unroll
            for (int c = 0; c < 8; ++c) acc[r][c] = 0.0f;

        #pragma unroll 2
        for (int i4 = 0; i4 < DIM; i4 += 4) {
            float4 xv[8], ev[8];
            #pragma unroll
            for (int r = 0; r < 8; ++r)
                xv[r] = *(const float4*)&xs[(tr + 16 * r) * PITCH + i4];
            #pragma unroll
            for (int c = 0; c < 8; ++c)
                ev[c] = *(const float4*)&cs[(tc + 16 * c) * PITCH + i4];
            #pragma unroll
            for (int q = 0; q < 4; ++q) {   // q outer: i-sequential chain per acc
                #pragma unroll
                for (int r = 0; r < 8; ++r) {
                    float xq = ((const float*)&xv[r])[q];
                    #pragma unroll
                    for (int c = 0; c < 8; ++c) {
                        float eq = ((const float*)&ev[c])[q];
                        acc[r][c] = __fmaf_rn(xq, eq, acc[r][c]);
                    }
                }
            }
        }

        // d = fl(fl(A+B) - 2*acc); merge packed key into running row minima
        float av[8];
        #pragma unroll
        for (int r = 0; r < 8; ++r) av[r] = anorm[tr + 16 * r];
        #pragma unroll
        for (int c = 0; c < 8; ++c) {
            const int kk = kc + tc + 16 * c;
            const float b2 = bnorm[kk];
            #pragma unroll
            for (int r = 0; r < 8; ++r) {
                float t1 = __fadd_rn(av[r], b2);
                float d  = __fsub_rn(t1, __fmul_rn(2.0f, acc[r][c]));
                unsigned long long key =
                    ((unsigned long long)fmap32(d) << 12) | (unsigned long long)kk;
                rowmin[r] = (key < rowmin[r]) ? key : rowmin[r];
            }
        }
    }

    // ---- reduce across the 16 code-groups (lanes sharing tr) ----
    #pragma unroll
    for (int r = 0; r < 8; ++r) {
        unsigned long long kmin = rowmin[r];
        #pragma unroll
        for (int off = 1; off < 16; off <<= 1) {
            unsigned long long o = __shfl_xor(kmin, off, 64);
            kmin = (o < kmin) ? o : kmin;
        }
        rowmin[r] = kmin;
    }
    if (tc == 0) {
        double loss_part = 0.0;
        #pragma unroll
        for (int r = 0; r < 8; ++r) {
            kstar[tr + 16 * r] = (int)(rowmin[r] & 0xFFFULL);
            loss_part += (double)funmap32((unsigned int)(rowmin[r] >> 12));
        }
        lossred[tr] = loss_part;
    }
    __syncthreads();

    // ---- epilogue ----
    if (tid < MTILE) out_idx[r0 + tid] = (float)kstar[tid];

    const int bb = r0 / T_LEN;
    const int t0 = r0 % T_LEN;
    #pragma unroll
    for (int it = 0; it < (MTILE * DIM) / THREADS; ++it) {  // 32
        int idx = it * THREADS + tid;
        int d = idx >> 7, t = idx & 127;
        out_q[((size_t)bb * DIM + d) * T_LEN + (t0 + t)] = cb[(size_t)kstar[t] * DIM + d];
    }
    if (tid == 0) {
        double s = 0.0;
        #pragma unroll
        for (int i = 0; i < 16; ++i) s += lossred[i];
        atomicAdd(ws_loss, s);
    }
}

extern "C" void kernel_launch(void* const* d_in, const int* in_sizes, int n_in,
                              void* d_out, int out_size, void* d_ws, size_t ws_size,
                              hipStream_t stream) {
    const float* x  = (const float*)d_in[0];
    const float* cb = (const float*)d_in[1];
    float* out = (float*)d_out;

    const int n_x = in_sizes[0];           // 4194304
    const int n_rows = n_x / DIM;          // 65536

    float* out_q    = out;                    // [B, D, T]
    float* out_loss = out + (size_t)n_x;      // scalar
    float* out_idx  = out + (size_t)n_x + 1;  // [B, T] as float
    double* wsd = (double*)d_ws;

    vq_init_ws<<<1, 1, 0, stream>>>(wsd);
    vq_main<<<n_rows / MTILE, THREADS, 0, stream>>>(x, cb, out_q, out_idx, wsd);
    vq_finalize<<<1, 1, 0, stream>>>(wsd, out_loss, n_x);
}